// Round 5
// baseline (525.054 us; speedup 1.0000x reference)
//
#include <hip/hip_runtime.h>
#include <math.h>

#define C1F 1.0e-4f   // 0.01^2
#define C2F 9.0e-4f   // 0.03^2
#define TX 64
#define TY 4
#define NROWS (TY + 2)                       // 6
#define NSTAGE ((TY + 2) * (TX + 2))         // 396
#define LPAD 4

// acc layout: per scale i (0..3), base = i*8
//  +0: sum |left_est - lpy|      +1: sum |right_est - rpy|
//  +2: sum |rl_disp - dl|        +3: sum |lr_disp - dr|
//  +4: sum x-grad smooth (dl+dr) +5: sum y-grad smooth (dl+dr)
//  +6: sum ssim_l (clipped)      +7: sum ssim_r

struct ScaleArgs {
    const float* disp;   // scale-res disparity
    const float* lp;     // scale-res left image (pyramid for i>0)
    const float* rp;     // scale-res right image
    int h, w, nx, ny, blk0, accoff, ntiles;
    float dmax;          // fast-path disparity bound (reach/(w-1))
};

__device__ __forceinline__ float2 f2(float v) { return make_float2(v, v); }

// full version: validity masks + clamps (edge tiles / fallback)
__device__ __forceinline__ void warp_coeffs(float px, int W, int& i0, int& i1,
                                            float& w0, float& w1) {
    float x0f = floorf(px);
    float f = px - x0f;
    int x0i = (int)x0f;
    int x1i = x0i + 1;
    float v0 = (x0i >= 0 && x0i < W) ? 1.f : 0.f;
    float v1 = (x1i >= 0 && x1i < W) ? 1.f : 0.f;
    i0 = min(max(x0i, 0), W - 1);
    i1 = min(max(x1i, 0), W - 1);
    w0 = v0 * (1.f - f);
    w1 = v1 * f;
}

// safe version: tile geometry + ok-range guarantee px in [0, W-1]
// (bit-exact with full version in that regime: v0=v1=1, no clamping active;
//  the only divergence is px==W-1 exactly, where w1=f=0 zeroes the i1 tap)
__device__ __forceinline__ void warp_coeffs_safe(float px, int& i0, int& i1,
                                                 float& w0, float& w1) {
    float x0f = floorf(px);
    float f = px - x0f;
    i0 = (int)x0f;
    i1 = i0 + 1;
    w0 = 1.f - f;
    w1 = f;
}

template<int N>
__device__ __forceinline__ void block_acc(const float* vals, float* gacc) {
    __shared__ float sacc[N];
    if (threadIdx.x < N) sacc[threadIdx.x] = 0.f;
    __syncthreads();
#pragma unroll
    for (int k = 0; k < N; ++k) {
        float v = vals[k];
#pragma unroll
        for (int off = 32; off > 0; off >>= 1) v += __shfl_down(v, off, 64);
        if ((threadIdx.x & 63) == 0) atomicAdd(&sacc[k], v);
    }
    __syncthreads();
    if (threadIdx.x < N) atomicAdd(&gacc[threadIdx.x], sacc[threadIdx.x]);
}

// Bijective XCD-chunked swizzle (m204 form).
__device__ __forceinline__ int xcd_swz(int orig, int n) {
    int q = n >> 3, r = n & 7;
    int x = orig & 7;
    int base = (x < r) ? x * (q + 1) : r * (q + 1) + (x - r) * q;
    return base + (orig >> 3);
}

__global__ void k_zero(float* acc) {
    if (threadIdx.x < 64) acc[threadIdx.x] = 0.f;
}

__device__ __forceinline__ bool rng_ok(float v, float dmax) {
    return (v >= 0.f) && (v <= dmax);   // NaN -> false
}

// ---- fused loss tile with LDS-staged gather stripes + packed float4 simg ----
// simg[c][slot] = (le, re, lv, rv): one b128 read per window point in the hot
// SSIM loop (round-0 packing) while keeping round-4's stripe staging (FETCH-
// optimal).  Index-bound analysis (interior 'safe' tiles, d <= dmax):
//   build/LR left-gather:  a in [5, SW-4)   right-gather: b in [?, SW-3)
// so all LDS fast-path indices stay inside the stripe arrays; the only
// exception is the measure-zero px==W-1-exact case whose tap weight is 0.
template<int SW, int RPAD, int REACH>
__device__ void fused_tile(const ScaleArgs& sa, int t, float* __restrict__ accbase,
                           float* __restrict__ sL, float* __restrict__ sR,
                           float* __restrict__ sdl, float* __restrict__ sdr,
                           float4* __restrict__ simg, int* __restrict__ sok) {
    constexpr int SW4 = SW / 4;
    const int h = sa.h, w = sa.w;
    float* acc = accbase + sa.accoff;

    const int tileX = t % sa.nx;
    int t2 = t / sa.nx;
    const int tileY = t2 % sa.ny;
    const int b = t2 / sa.ny;

    const int xo0 = tileX * TX, yo0 = tileY * TY;
    const int tid = threadIdx.x;
    const float Wm1 = (float)(w - 1);
    const float invWm1 = 1.f / Wm1;
    const int chs = h * w;
    const int lx0 = xo0 - LPAD;
    const int rx0 = xo0 - RPAD;
    const int gy0 = yo0 - 1;
    const float dmax = sa.dmax;

    const float* __restrict__ dl_base = sa.disp + (b * 2 + 0) * chs;
    const float* __restrict__ dr_base = sa.disp + (b * 2 + 1) * chs;
    const float* __restrict__ limg = sa.lp + b * 3 * chs;
    const float* __restrict__ rimg = sa.rp + b * 3 * chs;

    if (tid == 0) *sok = 1;
    __syncthreads();

    bool bad = false;
    const bool xint = (rx0 >= 0) && (lx0 + SW <= w);
    if (xint) {
        // ---- vectorized staging: (row, k4) shared by all 8 arrays ----
        for (int i = tid; i < NROWS * SW4; i += 256) {
            int r = i / SW4, k4 = i - r * SW4;
            int y = min(max(gy0 + r, 0), h - 1);
            int goL = y * w + lx0 + 4 * k4;
            int goR = y * w + rx0 + 4 * k4;
            int so = r * SW + 4 * k4;
#pragma unroll
            for (int c = 0; c < 3; ++c) {
                *(float4*)(sL + c * (NROWS * SW) + so) =
                    *(const float4*)(limg + c * chs + goL);
                *(float4*)(sR + c * (NROWS * SW) + so) =
                    *(const float4*)(rimg + c * chs + goR);
            }
            float4 vdl = *(const float4*)(dl_base + goL);
            float4 vdr = *(const float4*)(dr_base + goR);
            *(float4*)(sdl + so) = vdl;
            *(float4*)(sdr + so) = vdr;
            bad = bad || !rng_ok(vdl.x, dmax) || !rng_ok(vdl.y, dmax) ||
                         !rng_ok(vdl.z, dmax) || !rng_ok(vdl.w, dmax) ||
                         !rng_ok(vdr.x, dmax) || !rng_ok(vdr.y, dmax) ||
                         !rng_ok(vdr.z, dmax) || !rng_ok(vdr.w, dmax);
        }
    } else {
        // ---- scalar clamped staging (x-edge tiles only) ----
        for (int i = tid; i < NROWS * SW; i += 256) {
            int r = i / SW, k = i - r * SW;
            int y = min(max(gy0 + r, 0), h - 1);
            int xl = min(max(lx0 + k, 0), w - 1);
            int xr = min(max(rx0 + k, 0), w - 1);
            int yw = y * w;
#pragma unroll
            for (int c = 0; c < 3; ++c) {
                sL[c * (NROWS * SW) + i] = limg[c * chs + yw + xl];
                sR[c * (NROWS * SW) + i] = rimg[c * chs + yw + xr];
            }
            float vdl = dl_base[yw + xl];
            float vdr = dr_base[yw + xr];
            sdl[i] = vdl;
            sdr[i] = vdr;
            bad = bad || !rng_ok(vdl, dmax) || !rng_ok(vdr, dmax);
        }
    }
    if (bad) *sok = 0;
    __syncthreads();
    const bool ok = (*sok != 0);
    // interior tiles: all gather positions provably in-image and in-stripe
    const bool use_safe = ok && xint && (xo0 >= REACH + 1) &&
                          (xo0 + TX + REACH + 1 <= w);

    // ---- build packed estimate tile (le,re,lv,rv) per halo slot ----
    for (int i = tid; i < NSTAGE; i += 256) {
        int sx = i % (TX + 2);
        int sy = i / (TX + 2);
        int xr_ = xo0 - 1 + sx;
        int x = use_safe ? xr_ : min(max(xr_, 0), w - 1);
        float dl = sdl[sy * SW + (x - lx0)];
        float dr = sdr[sy * SW + (x - rx0)];
        float xb = (float)x * invWm1;
        int i0L, i1L, i0R, i1R;
        float w0L, w1L, w0R, w1R;
        if (use_safe) {
            warp_coeffs_safe((xb - dl) * Wm1, i0L, i1L, w0L, w1L);
            warp_coeffs_safe((xb + dr) * Wm1, i0R, i1R, w0R, w1R);
        } else {
            warp_coeffs((xb - dl) * Wm1, w, i0L, i1L, w0L, w1L);
            warp_coeffs((xb + dr) * Wm1, w, i0R, i1R, w0R, w1R);
        }
        if (ok) {
            int a0 = i0L - rx0, a1 = i1L - rx0;
            int b0 = i0R - lx0, b1 = i1R - lx0;
            int xl = x - lx0, xr2 = x - rx0;
#pragma unroll
            for (int c = 0; c < 3; ++c) {
                const float* R = sR + (c * NROWS + sy) * SW;
                const float* L = sL + (c * NROWS + sy) * SW;
                simg[c * NSTAGE + i] =
                    make_float4(R[a0] * w0L + R[a1] * w1L,
                                L[b0] * w0R + L[b1] * w1R,
                                L[xl], R[xr2]);
            }
        } else {
            int y = min(max(gy0 + sy, 0), h - 1);
            int rowoff = y * w;
#pragma unroll
            for (int c = 0; c < 3; ++c) {
                int co = c * chs + rowoff;
                simg[c * NSTAGE + i] =
                    make_float4(rimg[co + i0L] * w0L + rimg[co + i1L] * w1L,
                                limg[co + i0R] * w0R + limg[co + i1R] * w1R,
                                limg[co + x], rimg[co + x]);
            }
        }
    }
    __syncthreads();

    float sums[8] = {0.f, 0.f, 0.f, 0.f, 0.f, 0.f, 0.f, 0.f};
    const int tx = tid & (TX - 1), ty = tid >> 6;
    const int x = xo0 + tx, y = yo0 + ty;
    if (x < w && y < h) {
        const int s = (ty + 1) * (TX + 2) + tx + 1;
        const int rowd = (ty + 1) * SW;
        const int kL = tx + LPAD;       // x - lx0
        const int kR = tx + RPAD;       // x - rx0
        float dl = sdl[rowd + kL];
        float dr = sdr[rowd + kR];
        float4 ctr[3];
#pragma unroll
        for (int c = 0; c < 3; ++c) {
            float4 v = simg[c * NSTAGE + s];
            ctr[c] = v;
            sums[0] += fabsf(v.x - v.z);
            sums[1] += fabsf(v.y - v.w);
        }
        // LR consistency gathers
        {
            float xb = (float)x * invWm1;
            int i0, i1; float w0, w1;
            if (use_safe) warp_coeffs_safe((xb - dl) * Wm1, i0, i1, w0, w1);
            else          warp_coeffs((xb - dl) * Wm1, w, i0, i1, w0, w1);
            float rl;
            if (ok) {
                rl = sdr[rowd + (i0 - rx0)] * w0 + sdr[rowd + (i1 - rx0)] * w1;
            } else {
                const float* drr = dr_base + y * w;
                rl = drr[i0] * w0 + drr[i1] * w1;
            }
            sums[2] += fabsf(rl - dl);
            if (use_safe) warp_coeffs_safe((xb + dr) * Wm1, i0, i1, w0, w1);
            else          warp_coeffs((xb + dr) * Wm1, w, i0, i1, w0, w1);
            float lr;
            if (ok) {
                lr = sdl[rowd + (i0 - lx0)] * w0 + sdl[rowd + (i1 - lx0)] * w1;
            } else {
                const float* dlr = dl_base + y * w;
                lr = dlr[i0] * w0 + dlr[i1] * w1;
            }
            sums[3] += fabsf(lr - dr);
        }
        const float third = 1.f / 3.f;
        if (x < w - 1) {
            float dlx = sdl[rowd + kL + 1], drx = sdr[rowd + kR + 1];
            float ax = 0.f, ay = 0.f;
#pragma unroll
            for (int c = 0; c < 3; ++c) {
                float4 v1 = simg[c * NSTAGE + s + 1];
                ax += fabsf(ctr[c].z - v1.z);
                ay += fabsf(ctr[c].w - v1.w);
            }
            sums[4] += fabsf(dl - dlx) * __expf(-ax * third) +
                       fabsf(dr - drx) * __expf(-ay * third);
        }
        if (y < h - 1) {
            float dly = sdl[rowd + SW + kL], dry = sdr[rowd + SW + kR];
            float ax = 0.f, ay = 0.f;
#pragma unroll
            for (int c = 0; c < 3; ++c) {
                float4 v1 = simg[c * NSTAGE + s + (TX + 2)];
                ax += fabsf(ctr[c].z - v1.z);
                ay += fabsf(ctr[c].w - v1.w);
            }
            sums[5] += fabsf(dl - dly) * __expf(-ax * third) +
                       fabsf(dr - dry) * __expf(-ay * third);
        }
        if (x >= 1 && x <= w - 2 && y >= 1 && y <= h - 2) {
            const float2 inv9 = f2(1.f / 9.f);
            const float2 c1 = f2(C1F), c2 = f2(C2F);
            const float2 two = f2(2.f), one = f2(1.f), half_ = f2(0.5f);
#pragma unroll 1
            for (int c = 0; c < 3; ++c) {
                float2 sX = f2(0.f), sY = f2(0.f);
                float2 sXX = f2(0.f), sYY = f2(0.f), sXY = f2(0.f);
#pragma unroll
                for (int dy = 0; dy < 3; ++dy) {
                    const float4* eS = simg + c * NSTAGE + (ty + dy) * (TX + 2);
#pragma unroll
                    for (int dx = 0; dx < 3; ++dx) {
                        float4 v = eS[tx + dx];
                        sX.x += v.x;  sX.y += v.y;
                        sY.x += v.z;  sY.y += v.w;
                        sXX.x += v.x * v.x;  sXX.y += v.y * v.y;
                        sYY.x += v.z * v.z;  sYY.y += v.w * v.w;
                        sXY.x += v.x * v.z;  sXY.y += v.y * v.w;
                    }
                }
                float2 mx = make_float2(sX.x * inv9.x, sX.y * inv9.y);
                float2 my = make_float2(sY.x * inv9.x, sY.y * inv9.y);
                float2 vx = make_float2(sXX.x * inv9.x - mx.x * mx.x,
                                        sXX.y * inv9.y - mx.y * mx.y);
                float2 vy = make_float2(sYY.x * inv9.x - my.x * my.x,
                                        sYY.y * inv9.y - my.y * my.y);
                float2 vxy = make_float2(sXY.x * inv9.x - mx.x * my.x,
                                         sXY.y * inv9.y - mx.y * my.y);
                float2 num = make_float2((two.x * mx.x * my.x + c1.x) * (two.x * vxy.x + c2.x),
                                         (two.y * mx.y * my.y + c1.y) * (two.y * vxy.y + c2.y));
                float2 den = make_float2((mx.x * mx.x + my.x * my.x + c1.x) * (vx.x + vy.x + c2.x),
                                         (mx.y * mx.y + my.y * my.y + c1.y) * (vx.y + vy.y + c2.y));
                float2 ss = make_float2(num.x * __builtin_amdgcn_rcpf(den.x),
                                        num.y * __builtin_amdgcn_rcpf(den.y));
                float2 v = make_float2((one.x - ss.x) * half_.x,
                                       (one.y - ss.y) * half_.y);
                sums[6] += fminf(fmaxf(v.x, 0.f), 1.f);
                sums[7] += fminf(fmaxf(v.y, 0.f), 1.f);
            }
        }
    }
    block_acc<8>(sums, acc);
}

#define SW0 152   // lx0=xo0-4, rx0=xo0-84, reach 78 px (covers 0.1*767=76.7)
#define RP0 84
#define RCH0 78
#define SWB 112   // lx0=xo0-4, rx0=xo0-44, reach 40 px (covers 0.1*(w-1)<=38.3)
#define RPB 44
#define RCHB 40

// compile-time-dim bilinear resize for one output element
template<int OH, int OW, int HH, int WW>
__device__ __forceinline__ void resize_px(long long idx,
                                          const float* __restrict__ left,
                                          const float* __restrict__ right,
                                          float* __restrict__ lo,
                                          float* __restrict__ ro) {
    const long long half = (long long)16 * 3 * OH * OW;
    const float* src = left;
    float* dst = lo;
    if (idx >= half) { src = right; dst = ro; idx -= half; }
    int x = (int)(idx % OW);
    long long t = idx / OW;
    int y = (int)(t % OH);
    t /= OH;
    int c = (int)(t % 3);
    int b = (int)(t / 3);
    constexpr float sy = (float)(HH - 1) / (float)(OH - 1);
    constexpr float sx = (float)(WW - 1) / (float)(OW - 1);
    float fy = y * sy;
    float fx = x * sx;
    int y0 = (int)floorf(fy); float wy = fy - (float)y0;
    int x0 = (int)floorf(fx); float wx = fx - (float)x0;
    int y1 = min(y0 + 1, HH - 1); y0 = min(y0, HH - 1);
    int x1 = min(x0 + 1, WW - 1); x0 = min(x0, WW - 1);
    const float* p = src + ((long long)b * 3 + c) * HH * WW;
    float a00 = p[(long long)y0 * WW + x0];
    float a10 = p[(long long)y1 * WW + x0];
    float a01 = p[(long long)y0 * WW + x1];
    float a11 = p[(long long)y1 * WW + x1];
    float r0 = a00 * (1.f - wy) + a10 * wy;
    float r1 = a01 * (1.f - wy) + a11 * wy;
    dst[(((long long)b * 3 + c) * OH + y) * OW + x] = r0 * (1.f - wx) + r1 * wx;
}

#define N1E 7077888LL   // 2*16*3*192*384
#define N2E 1769472LL   // 2*16*3*96*192
#define N3E 442368LL    // 2*16*3*48*96
#define NRESB 36288     // (N1E+N2E+N3E)/256

// ---- Kernel A: resize blocks FIRST, then scale-0 fused tiles ----
__global__ void __launch_bounds__(256, 3)
k_fused0_resize(ScaleArgs s0, float* __restrict__ accbase,
                const float* __restrict__ left, const float* __restrict__ right,
                float* __restrict__ lo1, float* __restrict__ ro1,
                float* __restrict__ lo2, float* __restrict__ ro2,
                float* __restrict__ lo3, float* __restrict__ ro3,
                int nFusedBlocks) {
    __shared__ __align__(16) float sL[3 * NROWS * SW0];
    __shared__ __align__(16) float sR[3 * NROWS * SW0];
    __shared__ __align__(16) float sdl[NROWS * SW0];
    __shared__ __align__(16) float sdr[NROWS * SW0];
    __shared__ __align__(16) float4 simg[3 * NSTAGE];
    __shared__ int sok;

    int blk = (int)blockIdx.x;
    if (blk < NRESB) {
        long long idx = (long long)blk * 256 + threadIdx.x;
        if (idx < N1E)
            resize_px<192, 384, 384, 768>(idx, left, right, lo1, ro1);
        else if (idx < N1E + N2E)
            resize_px<96, 192, 384, 768>(idx - N1E, left, right, lo2, ro2);
        else
            resize_px<48, 96, 384, 768>(idx - N1E - N2E, left, right, lo3, ro3);
        return;
    }
    int t = xcd_swz(blk - NRESB, nFusedBlocks);
    fused_tile<SW0, RP0, RCH0>(s0, t, accbase, sL, sR, sdl, sdr, simg, &sok);
}

// ---- Kernel B: scales 1-3 fused (reads pyramid) ----
__global__ void __launch_bounds__(256, 3)
k_fused_small(ScaleArgs s1, ScaleArgs s2, ScaleArgs s3,
              float* __restrict__ accbase) {
    __shared__ __align__(16) float sL[3 * NROWS * SWB];
    __shared__ __align__(16) float sR[3 * NROWS * SWB];
    __shared__ __align__(16) float sdl[NROWS * SWB];
    __shared__ __align__(16) float sdr[NROWS * SWB];
    __shared__ __align__(16) float4 simg[3 * NSTAGE];
    __shared__ int sok;

    ScaleArgs sa;
    {
        int blk = (int)blockIdx.x;
        if (blk >= s3.blk0)      sa = s3;
        else if (blk >= s2.blk0) sa = s2;
        else                     sa = s1;
    }
    int t = xcd_swz((int)blockIdx.x - sa.blk0, sa.ntiles);
    fused_tile<SWB, RPB, RCHB>(sa, t, accbase, sL, sR, sdl, sdr, simg, &sok);
}

__global__ void k_final(const float* __restrict__ acc, float* __restrict__ out,
                        int B, int H, int W) {
    if (threadIdx.x != 0 || blockIdx.x != 0) return;
    float img = 0.f, lr = 0.f, sm = 0.f;
    for (int i = 0; i < 4; ++i) {
        int r = 1 << i;
        int h = H / r, w = W / r;
        const float* a = acc + i * 8;
        float Nl1 = (float)B * 3.f * (float)h * (float)w;
        float Nss = (float)B * 3.f * (float)(h - 2) * (float)(w - 2);
        float Nlr = (float)B * (float)h * (float)w;
        float Nsx = (float)B * (float)h * (float)(w - 1);
        float Nsy = (float)B * (float)(h - 1) * (float)w;
        img += 0.5f * (a[6] / Nss) + 0.5f * (a[0] / Nl1)
             + 0.5f * (a[7] / Nss) + 0.5f * (a[1] / Nl1);
        lr += a[2] / Nlr + a[3] / Nlr;
        sm += (a[4] / Nsx + a[5] / Nsy) / (float)r;
    }
    out[0] = img + 0.1f * sm + 1.0f * lr;
}

extern "C" void kernel_launch(void* const* d_in, const int* in_sizes, int n_in,
                              void* d_out, int out_size, void* d_ws, size_t ws_size,
                              hipStream_t stream) {
    const int B = 16, H = 384, W = 768;
    const float* disp[4] = {(const float*)d_in[0], (const float*)d_in[1],
                            (const float*)d_in[2], (const float*)d_in[3]};
    const float* left = (const float*)d_in[4];
    const float* right = (const float*)d_in[5];
    float* out = (float*)d_out;

    float* acc = (float*)d_ws;
    float* pyr = acc + 256;
    long long sz1 = (long long)B * 3 * (H / 2) * (W / 2);
    long long sz2 = (long long)B * 3 * (H / 4) * (W / 4);
    long long sz3 = (long long)B * 3 * (H / 8) * (W / 8);
    float* lp1 = pyr;
    float* rp1 = lp1 + sz1;
    float* lp2 = rp1 + sz1;
    float* rp2 = lp2 + sz2;
    float* lp3 = rp2 + sz2;
    float* rp3 = lp3 + sz3;

    const float* lp[4] = {left, lp1, lp2, lp3};
    const float* rp[4] = {right, rp1, rp2, rp3};
    // fast-path reach in px: scale0 78 (SW0/RP0), scales1-3 40 (SWB/RPB)
    const float reach_tab[4] = {78.f, 40.f, 40.f, 40.f};
    ScaleArgs sa[4];
    for (int i = 0; i < 4; ++i) {
        int r = 1 << i;
        int h = H / r, w = W / r;
        sa[i].disp = disp[i];
        sa[i].lp = lp[i];
        sa[i].rp = rp[i];
        sa[i].h = h;
        sa[i].w = w;
        sa[i].nx = (w + TX - 1) / TX;
        sa[i].ny = (h + TY - 1) / TY;
        sa[i].accoff = i * 8;
        sa[i].ntiles = sa[i].nx * sa[i].ny * B;
        sa[i].blk0 = 0;
        sa[i].dmax = reach_tab[i] / (float)(w - 1);
    }

    hipLaunchKernelGGL(k_zero, dim3(1), dim3(64), 0, stream, acc);

    // Kernel A: resize first, then scale-0 fused tiles
    {
        int nFused = sa[0].ntiles;
        hipLaunchKernelGGL(k_fused0_resize, dim3((unsigned)(NRESB + nFused)), dim3(256), 0, stream,
                           sa[0], acc, left, right, lp1, rp1, lp2, rp2, lp3, rp3,
                           nFused);
    }

    // Kernel B: scales 1-3 fused
    {
        int b1 = sa[1].ntiles;
        int b2 = sa[2].ntiles;
        int b3 = sa[3].ntiles;
        sa[1].blk0 = 0;
        sa[2].blk0 = b1;
        sa[3].blk0 = b1 + b2;
        hipLaunchKernelGGL(k_fused_small, dim3((unsigned)(b1 + b2 + b3)), dim3(256), 0, stream,
                           sa[1], sa[2], sa[3], acc);
    }
    hipLaunchKernelGGL(k_final, dim3(1), dim3(64), 0, stream, acc, out, B, H, W);
}